// Round 1
// 433.525 us; speedup vs baseline: 1.0006x; 1.0006x over previous
//
#include <hip/hip_runtime.h>
#include <hip/hip_fp16.h>

// ---------------------------------------------------------------------------
// DUPLEX GAT, round 10.
//   - dst-CSR build once (hist + parallel scan + fill; packed int4 edge recs
//     now {src, dst, w_am, w_ph}); scan3 also seeds cursor (memcpy removed).
//   - W prep: 4 weight mats -> fp16 Wt[n][k] (MFMA B-frags contiguous).
//   - Per layer (both channels per dispatch):
//       GEMM (MFMA f16, fp32 acc): 128x128 tile, two 64-wide K LDS phases;
//         epilogue: acc -> LDS fp16 -> coalesced ft + fused fp32 el/er dots.
//       coef: NEW edge-parallel pass, one thread per edge computes
//         x[e][h] = exp(leaky(el[src]+er[dst])) for both channels (fp32,
//         coalesced writes). 64x denser VALU use than computing these
//         per-head values inside the 64-lane gather wave (16x replication).
//       gather: one wave per (node, channel); scalar-addressed inner loop.
//         Softmax denominator factors out: out = (sum x*w*ft) / (sum x),
//         so the loop is now just {load x (broadcast dword), load ft half2,
//         l += x, cv = x*w, 2 fma} ~5-6 VALU/edge vs ~13 before.
// ---------------------------------------------------------------------------

typedef _Float16 f16x8 __attribute__((ext_vector_type(8)));
typedef float f32x4 __attribute__((ext_vector_type(4)));

struct GemmP { const void* X; const __half* Wt; const float *al, *ar; __half* Y; float *el, *er; };
struct ChP   { const __half* ft; const float* X; const float* bias; void* out; };
struct CoefP { const float *el, *er; float* X; };

__global__ void hist_kernel(const int* __restrict__ dst, int* __restrict__ counts, int E) {
  int e = blockIdx.x * blockDim.x + threadIdx.x;
  if (e < E) atomicAdd(&counts[dst[e]], 1);
}

__global__ __launch_bounds__(256) void scan1_kernel(const int* __restrict__ counts,
                                                    int* __restrict__ incl,
                                                    int* __restrict__ bsum, int n) {
  __shared__ int lds[256];
  int i = blockIdx.x * 256 + threadIdx.x;
  int v = (i < n) ? counts[i] : 0;
  lds[threadIdx.x] = v;
  __syncthreads();
  for (int off = 1; off < 256; off <<= 1) {
    int t = (threadIdx.x >= off) ? lds[threadIdx.x - off] : 0;
    __syncthreads();
    lds[threadIdx.x] += t;
    __syncthreads();
  }
  if (i < n) incl[i] = lds[threadIdx.x];
  if (threadIdx.x == 255) bsum[blockIdx.x] = lds[255];
}

__global__ __launch_bounds__(256) void scan2_kernel(int* __restrict__ bsum, int nb) {
  __shared__ int lds[256];
  int carry = 0;
  for (int base = 0; base < nb; base += 256) {
    int i = base + threadIdx.x;
    int v = (i < nb) ? bsum[i] : 0;
    lds[threadIdx.x] = v;
    __syncthreads();
    for (int off = 1; off < 256; off <<= 1) {
      int t = (threadIdx.x >= off) ? lds[threadIdx.x - off] : 0;
      __syncthreads();
      lds[threadIdx.x] += t;
      __syncthreads();
    }
    if (i < nb) bsum[i] = carry + lds[threadIdx.x] - v;  // exclusive
    carry += lds[255];
    __syncthreads();
  }
}

__global__ void scan3_kernel(const int* __restrict__ counts, const int* __restrict__ incl,
                             const int* __restrict__ bsum_ex, int* __restrict__ offsets,
                             int* __restrict__ cursor, int n, int E) {
  int i = blockIdx.x * blockDim.x + threadIdx.x;
  if (i < n) {
    int v = incl[i] - counts[i] + bsum_ex[i >> 8];
    offsets[i] = v;
    cursor[i] = v;  // seed fill cursor here (replaces D2D memcpy dispatch)
  }
  if (i == 0) offsets[n] = E;
}

__global__ void fill_kernel(const int* __restrict__ src, const int* __restrict__ dst,
                            const float* __restrict__ exist, const float* __restrict__ am_exist,
                            int* __restrict__ cursor, int4* __restrict__ edge16, int E) {
  int e = blockIdx.x * blockDim.x + threadIdx.x;
  if (e >= E) return;
  int d = dst[e];
  int pos = atomicAdd(&cursor[d], 1);
  edge16[pos] = make_int4(src[e], d, __float_as_int(am_exist[e]), __float_as_int(exist[e]));
}

// Convert + transpose 4 weight matrices: Wt_m[nn][k] = (half)W_m[k][nn].
__global__ void wprep_kernel(const float* __restrict__ W0a, const float* __restrict__ W0p,
                             const float* __restrict__ W1a, const float* __restrict__ W1p,
                             __half* __restrict__ Wt) {
  int m = blockIdx.y;
  const float* W = (m == 0) ? W0a : (m == 1) ? W0p : (m == 2) ? W1a : W1p;
  __half* O = Wt + (size_t)m * 16384;
  int i = blockIdx.x * 256 + threadIdx.x;  // 0..16383
  int nn = i >> 7, k = i & 127;
  O[nn * 128 + k] = __float2half_rn(W[k * 128 + nn]);
}

// Y(fp16) = fp16(X) @ fp16(W), fp32 MFMA acc; fused fp32 el/er epilogue.
// AFP16: A operand already fp16 (layer 1) vs fp32->fp16 staging (layer 0).
template <int AFP16>
__global__ __launch_bounds__(256) void gemm_kernel(GemmP p0, GemmP p1, int n) {
  GemmP p = blockIdx.y ? p1 : p0;
  constexpr int LDH = 72;   // staging stride (halves)
  constexpr int LDE = 136;  // epilogue stride (halves)
  __shared__ __half lds[2 * 128 * LDH];  // 36,864 B
  __half* As = lds;
  __half* Ws = lds + 128 * LDH;
  int t = threadIdx.x;
  int row0 = blockIdx.x << 7;
  int wv = t >> 6, lane = t & 63;
  int m = lane & 15, q = lane >> 4;

  f32x4 acc[2][8];
#pragma unroll
  for (int rt = 0; rt < 2; ++rt)
#pragma unroll
    for (int ct = 0; ct < 8; ++ct) acc[rt][ct] = (f32x4){0.f, 0.f, 0.f, 0.f};

#pragma unroll
  for (int kh = 0; kh < 2; ++kh) {
    __syncthreads();  // protect previous phase's fragment reads
    if (AFP16) {
      const __half* Xh = (const __half*)p.X;
#pragma unroll
      for (int i = 0; i < 4; ++i) {
        int c = t + (i << 8);  // 0..1023 chunks of 8 halves
        int r = c >> 3, o8 = c & 7;
        uint4 v = make_uint4(0, 0, 0, 0);
        if (row0 + r < n)
          v = *(const uint4*)(Xh + (size_t)(row0 + r) * 128 + (kh << 6) + (o8 << 3));
        *(uint4*)(As + r * LDH + (o8 << 3)) = v;
      }
    } else {
      const float* Xf = (const float*)p.X;
#pragma unroll
      for (int i = 0; i < 8; ++i) {
        int c = t + (i << 8);  // 0..2047 float4-chunks
        int r = c >> 4, f4 = c & 15;
        float4 v = make_float4(0.f, 0.f, 0.f, 0.f);
        if (row0 + r < n)
          v = *(const float4*)(Xf + (size_t)(row0 + r) * 128 + (kh << 6) + (f4 << 2));
        union { __half h[4]; uint2 u; } pk;
        pk.h[0] = __float2half_rn(v.x); pk.h[1] = __float2half_rn(v.y);
        pk.h[2] = __float2half_rn(v.z); pk.h[3] = __float2half_rn(v.w);
        *(uint2*)(As + r * LDH + (f4 << 2)) = pk.u;
      }
    }
    // stage Wt: 128 n-rows x 64 k (already fp16)
#pragma unroll
    for (int i = 0; i < 4; ++i) {
      int c = t + (i << 8);
      int r = c >> 3, o8 = c & 7;
      uint4 v = *(const uint4*)(p.Wt + (size_t)r * 128 + (kh << 6) + (o8 << 3));
      *(uint4*)(Ws + r * LDH + (o8 << 3)) = v;
    }
    __syncthreads();
#pragma unroll
    for (int kc = 0; kc < 2; ++kc) {
      f16x8 a0 = *(const f16x8*)(As + (wv * 32 + m) * LDH + kc * 32 + q * 8);
      f16x8 a1 = *(const f16x8*)(As + (wv * 32 + 16 + m) * LDH + kc * 32 + q * 8);
#pragma unroll
      for (int ct = 0; ct < 8; ++ct) {
        f16x8 b = *(const f16x8*)(Ws + (ct * 16 + m) * LDH + kc * 32 + q * 8);
        acc[0][ct] = __builtin_amdgcn_mfma_f32_16x16x32_f16(a0, b, acc[0][ct], 0, 0, 0);
        acc[1][ct] = __builtin_amdgcn_mfma_f32_16x16x32_f16(a1, b, acc[1][ct], 0, 0, 0);
      }
    }
  }
  // ---- epilogue: acc -> LDS fp16 (C/D layout: col=lane&15, row=quad*4+reg) ----
  __syncthreads();
#pragma unroll
  for (int rt = 0; rt < 2; ++rt) {
    int rbase = wv * 32 + rt * 16 + q * 4;
#pragma unroll
    for (int ct = 0; ct < 8; ++ct) {
      int col = ct * 16 + m;
#pragma unroll
      for (int r = 0; r < 4; ++r)
        lds[(rbase + r) * LDE + col] = __float2half_rn(acc[rt][ct][r]);
    }
  }
  __syncthreads();
  // 2 threads per row: half = cols 0..63 / 64..127. ft store + el/er head-dots.
  {
    int r = t & 127;
    int half = t >> 7;
    int row = row0 + r;
    if (row < n) {
      float e0 = 0.f, e1 = 0.f, r0 = 0.f, r1 = 0.f;
#pragma unroll
      for (int i = 0; i < 8; ++i) {
        int cbase = half * 64 + i * 8;
        f16x8 v = *(const f16x8*)(lds + r * LDE + cbase);
        *(uint4*)(p.Y + (size_t)row * 128 + cbase) = *(const uint4*)&v;
#pragma unroll
        for (int j = 0; j < 8; ++j) {
          float f = (float)v[j];
          float av = p.al[cbase + j];
          float rv = p.ar[cbase + j];
          if (((i * 8 + j) >> 5) == 0) { e0 = fmaf(f, av, e0); r0 = fmaf(f, rv, r0); }
          else                         { e1 = fmaf(f, av, e1); r1 = fmaf(f, rv, r1); }
        }
      }
      *(float2*)(p.el + (size_t)row * 4 + half * 2) = make_float2(e0, e1);
      *(float2*)(p.er + (size_t)row * 4 + half * 2) = make_float2(r0, r1);
    }
  }
}

// Edge-parallel softmax-logit pass: one thread per edge, both channels.
// X[e][h] = exp(leaky(el[src][h] + er[dst][h])), fp32, CSR edge order.
// el/er arrays are 800 KB each -> L2-resident, so the random s/d reads are
// cheap; writes are fully coalesced float4.
__global__ __launch_bounds__(256) void coef_kernel(CoefP a, CoefP b,
                                                   const int4* __restrict__ edge16, int E) {
  int e = blockIdx.x * 256 + threadIdx.x;
  if (e >= E) return;
  int4 r = edge16[e];
  int s = r.x, d = r.y;
  {
    float4 el = *(const float4*)(a.el + (size_t)s * 4);
    float4 er = *(const float4*)(a.er + (size_t)d * 4);
    float4 x;
    float v;
    v = el.x + er.x; v = (v > 0.f) ? v : 0.2f * v; x.x = __expf(v);
    v = el.y + er.y; v = (v > 0.f) ? v : 0.2f * v; x.y = __expf(v);
    v = el.z + er.z; v = (v > 0.f) ? v : 0.2f * v; x.z = __expf(v);
    v = el.w + er.w; v = (v > 0.f) ? v : 0.2f * v; x.w = __expf(v);
    *(float4*)(a.X + (size_t)e * 4) = x;
  }
  {
    float4 el = *(const float4*)(b.el + (size_t)s * 4);
    float4 er = *(const float4*)(b.er + (size_t)d * 4);
    float4 x;
    float v;
    v = el.x + er.x; v = (v > 0.f) ? v : 0.2f * v; x.x = __expf(v);
    v = el.y + er.y; v = (v > 0.f) ? v : 0.2f * v; x.y = __expf(v);
    v = el.z + er.z; v = (v > 0.f) ? v : 0.2f * v; x.z = __expf(v);
    v = el.w + er.w; v = (v > 0.f) ? v : 0.2f * v; x.w = __expf(v);
    *(float4*)(b.X + (size_t)e * 4) = x;
  }
}

// One wave per (node, channel). Block = 4 waves = 2 nodes x 2 channels.
// Scalar-addressed inner loop: loop counter is uniform -> edge records load
// through the scalar pipe; src sits in an SGPR so ft loads are
// SGPR-base + lane-offset. x loads are uniform-base + imm-offset broadcasts.
// Softmax denominator factored out: out = (sum x*w*ft) * (1/sum x) + bias.
template <int LAYER>
__global__ __launch_bounds__(256) void gather_kernel(ChP c0, ChP c1,
                                                     const int* __restrict__ offs,
                                                     const int4* __restrict__ edge16, int n) {
  int t = threadIdx.x;
  int w = t >> 6;
  int lane = t & 63;
  int node = blockIdx.x * 2 + (w >> 1);
  int ch = w & 1;
  if (node >= n) return;  // wave-uniform
  ChP P = ch ? c1 : c0;
  int hh = lane >> 4;

  int start = __builtin_amdgcn_readfirstlane(offs[node]);
  int end = __builtin_amdgcn_readfirstlane(offs[node + 1]);
  const __half2* ftbase = (const __half2*)P.ft;
  const float* Xb = P.X;

  float acc0 = 0.f, acc1 = 0.f, l = 0.f;
  int k = start;
  while (k + 8 <= end) {
    int4 ed[8];
#pragma unroll
    for (int j = 0; j < 8; ++j) ed[j] = edge16[k + j];
    const float* Xk = Xb + (size_t)k * 4;  // uniform batch base
    float xs[8];
#pragma unroll
    for (int j = 0; j < 8; ++j) xs[j] = Xk[j * 4 + hh];  // saddr + imm offset
#pragma unroll
    for (int j = 0; j < 8; ++j) {
      int s = ed[j].x;  // uniform -> SGPR
      float wgt = __int_as_float(ch ? ed[j].w : ed[j].z);
      __half2 fh = ftbase[(size_t)s * 64 + lane];  // saddr + lane*4
      float x = xs[j];
      l += x;
      float cv = x * wgt;
      acc0 = fmaf(cv, __low2float(fh), acc0);
      acc1 = fmaf(cv, __high2float(fh), acc1);
    }
    k += 8;
  }
  for (; k < end; ++k) {
    int4 ed = edge16[k];
    int s = ed.x;
    float wgt = __int_as_float(ch ? ed.w : ed.z);
    float x = Xb[(size_t)k * 4 + hh];
    __half2 fh = ftbase[(size_t)s * 64 + lane];
    l += x;
    float cv = x * wgt;
    acc0 = fmaf(cv, __low2float(fh), acc0);
    acc1 = fmaf(cv, __high2float(fh), acc1);
  }

  float rl = 1.f / fmaxf(l, 1e-9f);
  float2 b2 = *(const float2*)(P.bias + lane * 2);
  float v0 = fmaf(acc0, rl, b2.x);
  float v1 = fmaf(acc1, rl, b2.y);
  if (LAYER == 0) {
    // fp16 hidden buffer (GEMM-1 would quantize to fp16 anyway)
    __half2 h = __floats2half2_rn(fmaxf(v0, 0.f), fmaxf(v1, 0.f));
    ((__half2*)P.out)[(size_t)node * 64 + lane] = h;
  } else {
    v0 += __shfl_xor(v0, 16); v1 += __shfl_xor(v1, 16);
    v0 += __shfl_xor(v0, 32); v1 += __shfl_xor(v1, 32);
    if (lane < 16) {
      *(float2*)((float*)P.out + (size_t)node * 32 + lane * 2) =
          make_float2(0.25f * v0, 0.25f * v1);
    }
  }
}

extern "C" void kernel_launch(void* const* d_in, const int* in_sizes, int n_in,
                              void* d_out, int out_size, void* d_ws, size_t ws_size,
                              hipStream_t stream) {
  const float* x_am = (const float*)d_in[0];
  const float* x_ph = (const float*)d_in[1];
  const float* exist = (const float*)d_in[2];
  const float* am_exist = (const float*)d_in[3];
  const int* src = (const int*)d_in[4];
  const int* dst = (const int*)d_in[5];
  const float* W0a = (const float*)d_in[6];
  const float* al0a = (const float*)d_in[7];
  const float* ar0a = (const float*)d_in[8];
  const float* b0a = (const float*)d_in[9];
  const float* W0p = (const float*)d_in[10];
  const float* al0p = (const float*)d_in[11];
  const float* ar0p = (const float*)d_in[12];
  const float* b0p = (const float*)d_in[13];
  const float* W1a = (const float*)d_in[14];
  const float* al1a = (const float*)d_in[15];
  const float* ar1a = (const float*)d_in[16];
  const float* b1a = (const float*)d_in[17];
  const float* W1p = (const float*)d_in[18];
  const float* al1p = (const float*)d_in[19];
  const float* ar1p = (const float*)d_in[20];
  const float* b1p = (const float*)d_in[21];

  int n = in_sizes[0] / 128;  // 50000
  int E = in_sizes[2];        // 800000
  int N_pad = (n + 255) & ~255;
  int nb = (n + 255) / 256;
  int NB_pad = (nb + 63) & ~63;

  size_t szN = (size_t)N_pad * 4;
  size_t szOffs = (size_t)(N_pad + 8) * 4;
  size_t szE16 = (size_t)E * 16;
  size_t szFt16 = (size_t)n * 128 * 2;  // fp16 ft / hb
  size_t szEl = (size_t)N_pad * 4 * 4;
  size_t szWt = (size_t)4 * 128 * 128 * 2;
  size_t szX = (size_t)E * 16;  // fp32 x[e][4] coefficient array

  auto rnd = [](size_t b) { return (b + 255) & ~(size_t)255; };
  size_t fixed = 3 * rnd(szN) + rnd((size_t)NB_pad * 4) + rnd(szOffs) + rnd(szE16) +
                 4 * rnd(szEl) + rnd(szWt) + rnd(szX);
  bool dual = ws_size >= fixed + 4 * rnd(szFt16) + rnd(szX);

  char* p = (char*)d_ws;
  auto take = [&](size_t b) { char* q = p; p += (b + 255) & ~(size_t)255; return q; };
  int* counts = (int*)take(szN);
  int* cursor = (int*)take(szN);
  int* incl = (int*)take(szN);
  int* bsum = (int*)take((size_t)NB_pad * 4);
  int* offs = (int*)take(szOffs);
  int4* edge16 = (int4*)take(szE16);
  __half* Wt = (__half*)take(szWt);
  float* el_am = (float*)take(szEl);
  float* el_ph = (float*)take(szEl);
  float* er_am = (float*)take(szEl);
  float* er_ph = (float*)take(szEl);
  float* X_am = (float*)take(szX);
  float* X_ph = dual ? (float*)take(szX) : X_am;
  __half* ft_am = (__half*)take(szFt16);
  __half* ft_ph = dual ? (__half*)take(szFt16) : ft_am;
  __half* hb_am = (__half*)take(szFt16);
  __half* hb_ph = dual ? (__half*)take(szFt16) : hb_am;

  float* out_am = (float*)d_out;
  float* out_ph = out_am + (size_t)n * 32;

  // ---- CSR build + weight prep ----
  hipMemsetAsync(counts, 0, szN, stream);
  hist_kernel<<<(E + 255) / 256, 256, 0, stream>>>(dst, counts, E);
  wprep_kernel<<<dim3(64, 4), 256, 0, stream>>>(W0a, W0p, W1a, W1p, Wt);
  scan1_kernel<<<nb, 256, 0, stream>>>(counts, incl, bsum, n);
  scan2_kernel<<<1, 256, 0, stream>>>(bsum, nb);
  scan3_kernel<<<nb, 256, 0, stream>>>(counts, incl, bsum, offs, cursor, n, E);
  fill_kernel<<<(E + 255) / 256, 256, 0, stream>>>(src, dst, exist, am_exist,
                                                   cursor, edge16, E);

  int gg = (n + 127) / 128;
  int gw = (n + 1) / 2;
  int ce = (E + 255) / 256;
  GemmP g0a{x_am, Wt,          al0a, ar0a, ft_am, el_am, er_am};
  GemmP g0p{x_ph, Wt + 16384,  al0p, ar0p, ft_ph, el_ph, er_ph};
  GemmP g1a{hb_am, Wt + 32768, al1a, ar1a, ft_am, el_am, er_am};
  GemmP g1p{hb_ph, Wt + 49152, al1p, ar1p, ft_ph, el_ph, er_ph};
  CoefP ka{el_am, er_am, X_am};
  CoefP kp{el_ph, er_ph, X_ph};
  ChP c0a{ft_am, X_am, b0a, hb_am};
  ChP c0p{ft_ph, X_ph, b0p, hb_ph};
  ChP c1a{ft_am, X_am, b1a, out_am};
  ChP c1p{ft_ph, X_ph, b1p, out_ph};

  if (dual) {
    gemm_kernel<0><<<dim3(gg, 2), 256, 0, stream>>>(g0a, g0p, n);
    coef_kernel<<<ce, 256, 0, stream>>>(ka, kp, edge16, E);
    gather_kernel<0><<<gw, 256, 0, stream>>>(c0a, c0p, offs, edge16, n);
    gemm_kernel<1><<<dim3(gg, 2), 256, 0, stream>>>(g1a, g1p, n);
    coef_kernel<<<ce, 256, 0, stream>>>(ka, kp, edge16, E);
    gather_kernel<1><<<gw, 256, 0, stream>>>(c1a, c1p, offs, edge16, n);
  } else {
    // sequential fallback: both halves run the same channel (duplicate
    // identical writes, benign); buffers aliased above.
    gemm_kernel<0><<<dim3(gg, 2), 256, 0, stream>>>(g0a, g0a, n);
    coef_kernel<<<ce, 256, 0, stream>>>(ka, ka, edge16, E);
    gather_kernel<0><<<gw, 256, 0, stream>>>(c0a, c0a, offs, edge16, n);
    gemm_kernel<1><<<dim3(gg, 2), 256, 0, stream>>>(g1a, g1a, n);
    coef_kernel<<<ce, 256, 0, stream>>>(ka, ka, edge16, E);
    gather_kernel<1><<<gw, 256, 0, stream>>>(c1a, c1a, offs, edge16, n);
    gemm_kernel<0><<<dim3(gg, 2), 256, 0, stream>>>(g0p, g0p, n);
    coef_kernel<<<ce, 256, 0, stream>>>(kp, kp, edge16, E);
    gather_kernel<0><<<gw, 256, 0, stream>>>(c0p, c0p, offs, edge16, n);
    gemm_kernel<1><<<dim3(gg, 2), 256, 0, stream>>>(g1p, g1p, n);
    coef_kernel<<<ce, 256, 0, stream>>>(kp, kp, edge16, E);
    gather_kernel<1><<<gw, 256, 0, stream>>>(c1p, c1p, offs, edge16, n);
  }
}